// Round 5
// baseline (507.079 us; speedup 1.0000x reference)
//
#include <hip/hip_runtime.h>

#define CRF_B 256
#define CRF_L 1024
#define CRF_T 128

typedef __attribute__((ext_vector_type(8))) short bf16x8;
typedef __attribute__((ext_vector_type(4))) float f32x4;
typedef __attribute__((ext_vector_type(2))) short short2v;

#define MF(a, b, cacc) __builtin_amdgcn_mfma_f32_16x16x32_bf16((a), (b), (cacc), 0, 0, 0)

__global__ void zero_out_kernel(float* out) { out[0] = 0.0f; }

static __device__ __forceinline__ unsigned short f2bf(float x) {
    union { float f; unsigned u; } v; v.f = x;
    unsigned r = v.u + 0x7FFFu + ((v.u >> 16) & 1u);   // RNE
    return (unsigned short)(r >> 16);
}

static __device__ __forceinline__ short2v bmax2(short2v a, short2v b) {
    return __builtin_elementwise_max(a, b);   // v_pk_max_i16; bf16 >= 0 order-preserving
}
static __device__ __forceinline__ short2v fragmax(bf16x8 a) {
    short2v q0 = __builtin_shufflevector(a, a, 0, 1);
    short2v q1 = __builtin_shufflevector(a, a, 2, 3);
    short2v q2 = __builtin_shufflevector(a, a, 4, 5);
    short2v q3 = __builtin_shufflevector(a, a, 6, 7);
    return bmax2(bmax2(q0, q1), bmax2(q2, q3));
}

// One recurrence step. Writes x (bf16) of the previous row to LDS, re-reads
// as A-fragments, does the 128x128 matvec with 8 col-tiles x 4 k-tiles of
// 16x16x32 MFMA (broadcast-A: every lane's acc[0] = its col-tile result).
// nrm = max(x_prev) from the A-fragments (pk_i16 max + 2 shuffles).
// PF = raw feats row LV+1 at entry; reloaded with row LV+3.
#define STEP(LV, PF) do {                                                     \
    s_e[32 * g + c]      = f2bf(x[2 * g]);                                    \
    s_e[32 * g + 16 + c] = f2bf(x[2 * g + 1]);                                \
    bf16x8 A0_ = *(const bf16x8*)&s_e[ 0 + 8 * g];                            \
    bf16x8 A1_ = *(const bf16x8*)&s_e[32 + 8 * g];                            \
    bf16x8 A2_ = *(const bf16x8*)&s_e[64 + 8 * g];                            \
    bf16x8 A3_ = *(const bf16x8*)&s_e[96 + 8 * g];                            \
    short2v mx_ = bmax2(bmax2(fragmax(A0_), fragmax(A1_)),                    \
                        bmax2(fragmax(A2_), fragmax(A3_)));                   \
    unsigned mu_ = __builtin_bit_cast(unsigned, mx_);                         \
    float nrm = fmaxf(__builtin_bit_cast(float, mu_ << 16),                   \
                      __builtin_bit_cast(float, mu_ & 0xFFFF0000u));          \
    nrm = fmaxf(nrm, __shfl_xor(nrm, 16, 64));                                \
    nrm = fmaxf(nrm, __shfl_xor(nrm, 32, 64));                                \
    float sig_ = __builtin_amdgcn_rcpf(nrm);                                  \
    kap += __logf(nrm);                                                       \
    f32x4 dd[8];                                                              \
    _Pragma("unroll")                                                         \
    for (int ct = 0; ct < 8; ++ct) dd[ct] = MF(A0_, Bf[ct][0], Z);            \
    _Pragma("unroll")                                                         \
    for (int ct = 0; ct < 8; ++ct) dd[ct] = MF(A1_, Bf[ct][1], dd[ct]);       \
    _Pragma("unroll")                                                         \
    for (int ct = 0; ct < 8; ++ct) dd[ct] = MF(A2_, Bf[ct][2], dd[ct]);       \
    _Pragma("unroll")                                                         \
    for (int ct = 0; ct < 8; ++ct) dd[ct] = MF(A3_, Bf[ct][3], dd[ct]);       \
    int ldrow_ = (LV) + 3; if (ldrow_ > CRF_L - 1) ldrow_ = CRF_L - 1;        \
    const float* q_ = fb + (size_t)ldrow_ * CRF_T;                            \
    _Pragma("unroll")                                                         \
    for (int ct = 0; ct < 8; ++ct) {                                          \
        x[ct] = (F[ct] * sig_) * dd[ct][0];                                   \
        F[ct] = __expf(PF[ct]);                                               \
        PF[ct] = q_[16 * ct + c];                                             \
    }                                                                         \
} while (0)

// ONE wave (64 threads) per batch; no barriers anywhere in the scan.
// Lane (g = t>>4, c = t&15) holds B-fragments E[32kt+8g+e][16ct+c] and,
// after each step, x for cols {16ct + c}. Linear-domain recurrence:
// x_j = exp(p_j - kap), kap += log(max x) each step.
__global__ __launch_bounds__(64, 1) void forward_kernel(
    const float* __restrict__ trans, const float* __restrict__ feats,
    const int* __restrict__ mask, const int* __restrict__ tags,
    float* __restrict__ out)
{
    const int b = blockIdx.x;
    const int t = threadIdx.x;     // 0..63
    const int g = t >> 4;
    const int c = t & 15;

    __shared__ __align__(16) unsigned short s_e[CRF_T];

    // ---- per-batch length + gold score (single wave, shuffle-reduced) ----
    int cnt = 0; float gsum = 0.0f;
    const int base = b * CRF_L;
    for (int l = t; l < CRF_L; l += 64) {
        if (mask[base + l] != 0) {
            cnt++;
            int tg = tags[base + l];
            float gv = feats[(size_t)(base + l) * CRF_T + tg];
            if (l > 0) gv += trans[tags[base + l - 1] * CRF_T + tg];
            gsum += gv;
        }
    }
    for (int off = 32; off > 0; off >>= 1) {
        cnt  += __shfl_down(cnt, off, 64);
        gsum += __shfl_down(gsum, off, 64);
    }
    const int   len  = __shfl(cnt, 0, 64);
    const float gold = __shfl(gsum, 0, 64);

    // ---- B fragments: E = exp(trans), 8 col-tiles x 4 k-tiles (one-time) ----
    bf16x8 Bf[8][4];
#pragma unroll
    for (int ct = 0; ct < 8; ++ct)
#pragma unroll
        for (int kt = 0; kt < 4; ++kt)
#pragma unroll
            for (int e = 0; e < 8; ++e) {
                int k = 32 * kt + 8 * g + e;
                Bf[ct][kt][e] = (short)f2bf(__expf(trans[k * CRF_T + 16 * ct + c]));
            }

    const float* fb = feats + (size_t)b * CRF_L * CRF_T;

    // ---- init: x = exp(p0 - m0), kap = m0 ----
    float x[8];
#pragma unroll
    for (int ct = 0; ct < 8; ++ct) x[ct] = fb[16 * ct + c];
    float m0 = x[0];
#pragma unroll
    for (int ct = 1; ct < 8; ++ct) m0 = fmaxf(m0, x[ct]);
    m0 = fmaxf(m0, __shfl_xor(m0, 1, 64));
    m0 = fmaxf(m0, __shfl_xor(m0, 2, 64));
    m0 = fmaxf(m0, __shfl_xor(m0, 4, 64));
    m0 = fmaxf(m0, __shfl_xor(m0, 8, 64));
#pragma unroll
    for (int ct = 0; ct < 8; ++ct) x[ct] = __expf(x[ct] - m0);
    float kap = m0;

    // F = exp(feats row 1); pfA = raw row 2; pfB = raw row 3
    float F[8], pfA[8], pfB[8];
#pragma unroll
    for (int ct = 0; ct < 8; ++ct) {
        F[ct]   = __expf(fb[1 * CRF_T + 16 * ct + c]);
        pfA[ct] = fb[2 * CRF_T + 16 * ct + c];
        pfB[ct] = fb[3 * CRF_T + 16 * ct + c];
    }

    const f32x4 Z = {};

    int l = 1;
    for (; l + 1 < len; l += 2) {
        STEP(l,     pfA);
        STEP(l + 1, pfB);
    }
    if (l < len) STEP(l, pfA);

    // ---- final: forward = kap + log(sum_j x_j) ----
    float tot = ((x[0] + x[1]) + (x[2] + x[3])) + ((x[4] + x[5]) + (x[6] + x[7]));
    tot += __shfl_xor(tot, 1, 64);
    tot += __shfl_xor(tot, 2, 64);
    tot += __shfl_xor(tot, 4, 64);
    tot += __shfl_xor(tot, 8, 64);
    if (t == 0) atomicAdd(out, kap + __logf(tot) - gold);
}

extern "C" void kernel_launch(void* const* d_in, const int* in_sizes, int n_in,
                              void* d_out, int out_size, void* d_ws, size_t ws_size,
                              hipStream_t stream) {
    const float* trans = (const float*)d_in[0];
    const float* feats = (const float*)d_in[1];
    const int*   mask  = (const int*)d_in[2];
    const int*   tags  = (const int*)d_in[3];
    float*       out   = (float*)d_out;

    hipLaunchKernelGGL(zero_out_kernel, dim3(1), dim3(1), 0, stream, out);
    hipLaunchKernelGGL(forward_kernel, dim3(CRF_B), dim3(64), 0, stream,
                       trans, feats, mask, tags, out);
}

// Round 6
// 266.628 us; speedup vs baseline: 1.9018x; 1.9018x over previous
//
#include <hip/hip_runtime.h>

#define CRF_B 256
#define CRF_L 1024
#define CRF_T 128

typedef __attribute__((ext_vector_type(8))) short bf16x8;
typedef __attribute__((ext_vector_type(4))) float f32x4;
typedef __attribute__((ext_vector_type(2))) short short2v;

#define MF(a, b, cacc) __builtin_amdgcn_mfma_f32_16x16x32_bf16((a), (b), (cacc), 0, 0, 0)
// LDS-visibility barrier WITHOUT vmcnt drain (global prefetches stay in flight)
#define WG_BARRIER() asm volatile("s_waitcnt lgkmcnt(0)\n\ts_barrier" ::: "memory")

__global__ void zero_out_kernel(float* out) { out[0] = 0.0f; }

static __device__ __forceinline__ unsigned short f2bf(float x) {
    union { float f; unsigned u; } v; v.f = x;
    unsigned r = v.u + 0x7FFFu + ((v.u >> 16) & 1u);   // RNE
    return (unsigned short)(r >> 16);
}
static __device__ __forceinline__ short2v bmax2(short2v a, short2v b) {
    return __builtin_elementwise_max(a, b);   // v_pk_max_i16; bf16>=0 order-preserving
}
static __device__ __forceinline__ short2v fragmax(bf16x8 a) {
    short2v q0 = __builtin_shufflevector(a, a, 0, 1);
    short2v q1 = __builtin_shufflevector(a, a, 2, 3);
    short2v q2 = __builtin_shufflevector(a, a, 4, 5);
    short2v q3 = __builtin_shufflevector(a, a, 6, 7);
    return bmax2(bmax2(q0, q1), bmax2(q2, q3));
}

// One lockstep step for BOTH directions. Exactly one barrier, executed by all
// 512 threads. act_ is block-uniform per wave-group. fwd: x'=F*sig*(E^T x).
// bwd: publish v=F*x, x'=sig*(E v). nrm from own fragments (no shuffles).
#define BODY(S, P0, P1) do {                                                   \
    const int  sl_  = (S) & 1;                                                 \
    const bool act_ = isf || ((S) <= bsteps);                                  \
    if (act_) {                                                                \
        float v0_ = isf ? x0 : F0 * x0;                                        \
        float v1_ = isf ? x1 : F1 * x1;                                        \
        if (g == 0) { myse[sl_][c0] = f2bf(v0_); myse[sl_][c1] = f2bf(v1_); }  \
    }                                                                          \
    WG_BARRIER();                                                              \
    if (act_) {                                                                \
        bf16x8 A0_ = *(const bf16x8*)&myse[sl_][ 0 + 8 * g];                   \
        bf16x8 A1_ = *(const bf16x8*)&myse[sl_][32 + 8 * g];                   \
        bf16x8 A2_ = *(const bf16x8*)&myse[sl_][64 + 8 * g];                   \
        bf16x8 A3_ = *(const bf16x8*)&myse[sl_][96 + 8 * g];                   \
        short2v mx_ = bmax2(bmax2(fragmax(A0_), fragmax(A1_)),                 \
                            bmax2(fragmax(A2_), fragmax(A3_)));                \
        unsigned mu_ = __builtin_bit_cast(unsigned, mx_);                      \
        float nrm_ = fmaxf(__builtin_bit_cast(float, mu_ << 16),               \
                           __builtin_bit_cast(float, mu_ & 0xFFFF0000u));      \
        float sig_ = __builtin_amdgcn_rcpf(nrm_);                              \
        kap += __logf(nrm_);                                                   \
        f32x4 d0_ = MF(A0_, Bf[0][0], Z);                                      \
        f32x4 d1_ = MF(A0_, Bf[1][0], Z);                                      \
        d0_ = MF(A1_, Bf[0][1], d0_);  d1_ = MF(A1_, Bf[1][1], d1_);           \
        d0_ = MF(A2_, Bf[0][2], d0_);  d1_ = MF(A2_, Bf[1][2], d1_);           \
        d0_ = MF(A3_, Bf[0][3], d0_);  d1_ = MF(A3_, Bf[1][3], d1_);           \
        x0 = isf ? (F0 * sig_) * d0_[0] : sig_ * d0_[0];                       \
        x1 = isf ? (F1 * sig_) * d1_[0] : sig_ * d1_[0];                       \
        F0 = __expf(P0); F1 = __expf(P1);                                      \
        int rr_ = isf ? ((S) + 3) : (len - (S) - 3);                           \
        if (rr_ > CRF_L - 1) rr_ = CRF_L - 1;                                  \
        if (rr_ < 0) rr_ = 0;                                                  \
        P0 = fb[(size_t)rr_ * CRF_T + c0];                                     \
        P1 = fb[(size_t)rr_ * CRF_T + c1];                                     \
    }                                                                          \
} while (0)

// 256 blocks x 512 threads. Waves 0-3: forward half-chain (a_1..a_m).
// Waves 4-7: backward half-chain (b_{len-2}..b_m). logZ = kf+kb+log(sum xf*xb).
__global__ __launch_bounds__(512) void forward_kernel(
    const float* __restrict__ trans, const float* __restrict__ feats,
    const int* __restrict__ mask, const int* __restrict__ tags,
    float* __restrict__ out)
{
    const int b    = blockIdx.x;
    const int t    = threadIdx.x;
    const int w    = t >> 6;
    const int lane = t & 63;
    const int g    = lane >> 4;
    const int c    = lane & 15;
    const bool isf = (w < 4);
    const int wd   = isf ? w : (w - 4);
    const int c0   = 32 * wd + c;
    const int c1   = c0 + 16;

    __shared__ __align__(16) unsigned short s_ef[2][CRF_T];
    __shared__ __align__(16) unsigned short s_eb[2][CRF_T];
    __shared__ float s_xf[CRF_T], s_xb[CRF_T];
    __shared__ float s_gold, s_kf, s_kb;
    __shared__ int   s_len;

    unsigned short (*myse)[CRF_T] = isf ? s_ef : s_eb;

    if (t == 0) { s_len = 0; s_gold = 0.0f; }
    __syncthreads();

    // ---- per-batch length + gold score ----
    {
        int cnt = 0; float gsum = 0.0f;
        const int base = b * CRF_L;
        for (int l = t; l < CRF_L; l += 512) {
            if (mask[base + l] != 0) {
                cnt++;
                int tg = tags[base + l];
                float gv = feats[(size_t)(base + l) * CRF_T + tg];
                if (l > 0) gv += trans[tags[base + l - 1] * CRF_T + tg];
                gsum += gv;
            }
        }
        for (int off = 32; off > 0; off >>= 1) {
            cnt  += __shfl_down(cnt, off, 64);
            gsum += __shfl_down(gsum, off, 64);
        }
        if (lane == 0) { atomicAdd(&s_len, cnt); atomicAdd(&s_gold, gsum); }
    }

    // ---- B fragments: fwd = E[k][col], bwd = E[col][k] (transposed) ----
    bf16x8 Bf[2][4];
#pragma unroll
    for (int t2 = 0; t2 < 2; ++t2) {
        const int col = t2 ? c1 : c0;
#pragma unroll
        for (int kt = 0; kt < 4; ++kt)
#pragma unroll
            for (int e = 0; e < 8; ++e) {
                int k = 32 * kt + 8 * g + e;
                int idx = isf ? (k * CRF_T + col) : (col * CRF_T + k);
                Bf[t2][kt][e] = (short)f2bf(__expf(trans[idx]));
            }
    }

    __syncthreads();
    const int len    = s_len;
    const int m      = len >> 1;         // fwd steps
    const int bsteps = len - 1 - m;      // bwd steps (= m or m-1)
    const int nsteps = m;

    const float* fb = feats + (size_t)b * CRF_L * CRF_T;

    float x0, x1, F0, F1, pfA0, pfA1, pfB0, pfB1;
    float kap = 0.0f;
    if (isf) {
        x0 = __expf(fb[c0]);  x1 = __expf(fb[c1]);          // a_0 = exp(f_0)
        F0 = __expf(fb[CRF_T + c0]);  F1 = __expf(fb[CRF_T + c1]);
        pfA0 = fb[2 * CRF_T + c0];  pfA1 = fb[2 * CRF_T + c1];
        pfB0 = fb[3 * CRF_T + c0];  pfB1 = fb[3 * CRF_T + c1];
    } else {
        x0 = 1.0f;  x1 = 1.0f;                              // b_{len-1} = 1
        F0 = __expf(fb[(size_t)(len - 1) * CRF_T + c0]);
        F1 = __expf(fb[(size_t)(len - 1) * CRF_T + c1]);
        pfA0 = fb[(size_t)(len - 2) * CRF_T + c0];
        pfA1 = fb[(size_t)(len - 2) * CRF_T + c1];
        pfB0 = fb[(size_t)(len - 3) * CRF_T + c0];
        pfB1 = fb[(size_t)(len - 3) * CRF_T + c1];
    }

    const f32x4 Z = {};

    int s = 1;
    for (; s + 1 <= nsteps; s += 2) {
        BODY(s,     pfA0, pfA1);
        BODY(s + 1, pfB0, pfB1);
    }
    if (s <= nsteps) BODY(s, pfA0, pfA1);

    // ---- combine: Z = sum_j a_m[j] * b_m[j] ----
    if (g == 0) {
        if (isf) { s_xf[c0] = x0; s_xf[c1] = x1; }
        else     { s_xb[c0] = x0; s_xb[c1] = x1; }
    }
    if (t == 0)   s_kf = kap;
    if (t == 256) s_kb = kap;
    __syncthreads();
    if (w == 0) {
        float pr = s_xf[lane] * s_xb[lane] + s_xf[lane + 64] * s_xb[lane + 64];
        pr += __shfl_xor(pr, 1, 64);
        pr += __shfl_xor(pr, 2, 64);
        pr += __shfl_xor(pr, 4, 64);
        pr += __shfl_xor(pr, 8, 64);
        pr += __shfl_xor(pr, 16, 64);
        pr += __shfl_xor(pr, 32, 64);
        if (lane == 0)
            atomicAdd(out, s_kf + s_kb + __logf(pr) - s_gold);
    }
}

extern "C" void kernel_launch(void* const* d_in, const int* in_sizes, int n_in,
                              void* d_out, int out_size, void* d_ws, size_t ws_size,
                              hipStream_t stream) {
    const float* trans = (const float*)d_in[0];
    const float* feats = (const float*)d_in[1];
    const int*   mask  = (const int*)d_in[2];
    const int*   tags  = (const int*)d_in[3];
    float*       out   = (float*)d_out;

    hipLaunchKernelGGL(zero_out_kernel, dim3(1), dim3(1), 0, stream, out);
    hipLaunchKernelGGL(forward_kernel, dim3(CRF_B), dim3(512), 0, stream,
                       trans, feats, mask, tags, out);
}

// Round 7
// 184.412 us; speedup vs baseline: 2.7497x; 1.4458x over previous
//
#include <hip/hip_runtime.h>

#define CRF_B 256
#define CRF_L 1024
#define CRF_T 128
#define WS_STRIDE 260   // floats per batch: xf[128], xb[128], kf, kb, gold

typedef __attribute__((ext_vector_type(8))) short bf16x8;
typedef __attribute__((ext_vector_type(4))) float f32x4;
typedef __attribute__((ext_vector_type(2))) short short2v;

#define MF(a, b, cacc) __builtin_amdgcn_mfma_f32_16x16x32_bf16((a), (b), (cacc), 0, 0, 0)
// LDS-visibility barrier WITHOUT vmcnt drain (global prefetches stay in flight)
#define WG_BARRIER() asm volatile("s_waitcnt lgkmcnt(0)\n\ts_barrier" ::: "memory")

static __device__ __forceinline__ unsigned short f2bf(float x) {
    union { float f; unsigned u; } v; v.f = x;
    unsigned r = v.u + 0x7FFFu + ((v.u >> 16) & 1u);   // RNE
    return (unsigned short)(r >> 16);
}
static __device__ __forceinline__ short2v bmax2(short2v a, short2v b) {
    return __builtin_elementwise_max(a, b);   // v_pk_max_i16; bf16>=0 order-preserving
}
static __device__ __forceinline__ short2v fragmax(bf16x8 a) {
    short2v q0 = __builtin_shufflevector(a, a, 0, 1);
    short2v q1 = __builtin_shufflevector(a, a, 2, 3);
    short2v q2 = __builtin_shufflevector(a, a, 4, 5);
    short2v q3 = __builtin_shufflevector(a, a, 6, 7);
    return bmax2(bmax2(q0, q1), bmax2(q2, q3));
}

// One recurrence step. NORM is a compile-time flag: rescale + kap bookkeeping
// only every other step (growth per plain step bounded ~e^10; fp32/bf16 safe).
// fwd: publish x, x' = F*(E^T x)[*sig].  bwd: publish F*x, x' = (E v)[*sig].
#define STEP(S, P0, P1, NORM) do {                                             \
    const int sl_ = (S) & 1;                                                   \
    float v0_ = isf ? x0 : F0 * x0;                                            \
    float v1_ = isf ? x1 : F1 * x1;                                            \
    if (g == 0) { s_e[sl_][c0] = f2bf(v0_); s_e[sl_][c1] = f2bf(v1_); }        \
    WG_BARRIER();                                                              \
    bf16x8 A0_ = *(const bf16x8*)&s_e[sl_][ 0 + 8 * g];                        \
    bf16x8 A1_ = *(const bf16x8*)&s_e[sl_][32 + 8 * g];                        \
    bf16x8 A2_ = *(const bf16x8*)&s_e[sl_][64 + 8 * g];                        \
    bf16x8 A3_ = *(const bf16x8*)&s_e[sl_][96 + 8 * g];                        \
    f32x4 dA0_ = MF(A0_, Bf[0][0], Z);  f32x4 dB0_ = MF(A1_, Bf[0][1], Z);     \
    f32x4 dA1_ = MF(A0_, Bf[1][0], Z);  f32x4 dB1_ = MF(A1_, Bf[1][1], Z);     \
    dA0_ = MF(A2_, Bf[0][2], dA0_);  dB0_ = MF(A3_, Bf[0][3], dB0_);           \
    dA1_ = MF(A2_, Bf[1][2], dA1_);  dB1_ = MF(A3_, Bf[1][3], dB1_);           \
    float d0_ = dA0_[0] + dB0_[0];                                             \
    float d1_ = dA1_[0] + dB1_[0];                                             \
    if (NORM) {                                                                \
        short2v mx_ = bmax2(bmax2(fragmax(A0_), fragmax(A1_)),                 \
                            bmax2(fragmax(A2_), fragmax(A3_)));                \
        unsigned mu_ = __builtin_bit_cast(unsigned, mx_);                      \
        float nrm_ = fmaxf(__builtin_bit_cast(float, mu_ << 16),               \
                           __builtin_bit_cast(float, mu_ & 0xFFFF0000u));      \
        float sig_ = __builtin_amdgcn_rcpf(nrm_);                              \
        kap += __logf(nrm_);                                                   \
        d0_ *= sig_; d1_ *= sig_;                                              \
    }                                                                          \
    x0 = isf ? F0 * d0_ : d0_;                                                 \
    x1 = isf ? F1 * d1_ : d1_;                                                 \
    F0 = __expf(P0); F1 = __expf(P1);                                          \
    int rr_ = isf ? ((S) + 3) : (len - (S) - 3);                               \
    if (rr_ > CRF_L - 1) rr_ = CRF_L - 1;                                      \
    if (rr_ < 0) rr_ = 0;                                                      \
    P0 = fb[(size_t)rr_ * CRF_T + c0];                                         \
    P1 = fb[(size_t)rr_ * CRF_T + c1];                                         \
} while (0)

// 512 blocks x 256 threads: block = one direction of one batch.
// blockIdx: b = x>>1, dir = x&1 (0 = fwd a-chain, 1 = bwd b-chain).
// 2 independent blocks/CU -> phases interleave instead of lockstep-serializing.
__global__ __launch_bounds__(256, 2) void forward_kernel(
    const float* __restrict__ trans, const float* __restrict__ feats,
    const int* __restrict__ mask, const int* __restrict__ tags,
    float* __restrict__ ws)
{
    const int b    = blockIdx.x >> 1;
    const int dir  = blockIdx.x & 1;
    const bool isf = (dir == 0);
    const int t    = threadIdx.x;
    const int w    = t >> 6;
    const int lane = t & 63;
    const int g    = lane >> 4;
    const int c    = lane & 15;
    const int c0   = 32 * w + c;
    const int c1   = c0 + 16;

    __shared__ __align__(16) unsigned short s_e[2][CRF_T];
    __shared__ float s_gold;
    __shared__ int   s_len;

    if (t == 0) { s_len = 0; s_gold = 0.0f; }
    __syncthreads();

    // ---- per-batch length (+ gold score, fwd block only) ----
    {
        int cnt = 0; float gsum = 0.0f;
        const int base = b * CRF_L;
        for (int l = t; l < CRF_L; l += 256) {
            if (mask[base + l] != 0) {
                cnt++;
                if (isf) {
                    int tg = tags[base + l];
                    float gv = feats[(size_t)(base + l) * CRF_T + tg];
                    if (l > 0) gv += trans[tags[base + l - 1] * CRF_T + tg];
                    gsum += gv;
                }
            }
        }
        for (int off = 32; off > 0; off >>= 1) {
            cnt  += __shfl_down(cnt, off, 64);
            gsum += __shfl_down(gsum, off, 64);
        }
        if (lane == 0) { atomicAdd(&s_len, cnt); if (isf) atomicAdd(&s_gold, gsum); }
    }

    // ---- B fragments: fwd = E[k][col], bwd = E[col][k] (one-time) ----
    bf16x8 Bf[2][4];
#pragma unroll
    for (int t2 = 0; t2 < 2; ++t2) {
        const int col = t2 ? c1 : c0;
#pragma unroll
        for (int kt = 0; kt < 4; ++kt)
#pragma unroll
            for (int e = 0; e < 8; ++e) {
                int k = 32 * kt + 8 * g + e;
                int idx = isf ? (k * CRF_T + col) : (col * CRF_T + k);
                Bf[t2][kt][e] = (short)f2bf(__expf(trans[idx]));
            }
    }

    __syncthreads();
    const int len    = s_len;
    const int m      = len >> 1;               // fwd steps
    const int nsteps = isf ? m : (len - 1 - m);

    const float* fb = feats + (size_t)b * CRF_L * CRF_T;

    float x0, x1, F0, F1, pfA0, pfA1, pfB0, pfB1;
    float kap = 0.0f;
    if (isf) {
        x0 = __expf(fb[c0]);  x1 = __expf(fb[c1]);          // a_0 = exp(f_0)
        F0 = __expf(fb[CRF_T + c0]);  F1 = __expf(fb[CRF_T + c1]);
        pfA0 = fb[2 * CRF_T + c0];  pfA1 = fb[2 * CRF_T + c1];
        pfB0 = fb[3 * CRF_T + c0];  pfB1 = fb[3 * CRF_T + c1];
    } else {
        x0 = 1.0f;  x1 = 1.0f;                              // b_{len-1} = 1
        F0 = __expf(fb[(size_t)(len - 1) * CRF_T + c0]);
        F1 = __expf(fb[(size_t)(len - 1) * CRF_T + c1]);
        pfA0 = fb[(size_t)(len - 2) * CRF_T + c0];
        pfA1 = fb[(size_t)(len - 2) * CRF_T + c1];
        pfB0 = fb[(size_t)(len - 3) * CRF_T + c0];
        pfB1 = fb[(size_t)(len - 3) * CRF_T + c1];
    }

    const f32x4 Z = {};

    int s = 1;
    for (; s + 1 <= nsteps; s += 2) {
        STEP(s,     pfA0, pfA1, true);
        STEP(s + 1, pfB0, pfB1, false);
    }
    if (s <= nsteps) STEP(s, pfA0, pfA1, true);

    // ---- write this half-chain's state to workspace ----
    float* wsb = ws + (size_t)b * WS_STRIDE;
    if (g == 0) {
        wsb[dir * 128 + c0] = x0;
        wsb[dir * 128 + c1] = x1;
    }
    if (t == 0) {
        wsb[256 + dir] = kap;
        if (isf) wsb[258] = s_gold;
    }
}

// single block, thread t = batch t: loss_b = kf+kb+log(sum xf.xb) - gold
__global__ __launch_bounds__(256) void combine_kernel(
    const float* __restrict__ ws, float* __restrict__ out)
{
    const int t    = threadIdx.x;
    const int lane = t & 63;
    const int w    = t >> 6;
    const float4* pf = (const float4*)(ws + (size_t)t * WS_STRIDE);
    const float4* pb = pf + 32;
    float dot = 0.0f;
#pragma unroll
    for (int k = 0; k < 32; ++k) {
        float4 a = pf[k], bb = pb[k];
        dot += a.x * bb.x + a.y * bb.y + a.z * bb.z + a.w * bb.w;
    }
    const float* ps = ws + (size_t)t * WS_STRIDE;
    float val = ps[256] + ps[257] + __logf(dot) - ps[258];
    for (int off = 32; off > 0; off >>= 1) val += __shfl_down(val, off, 64);
    __shared__ float sw[4];
    if (lane == 0) sw[w] = val;
    __syncthreads();
    if (t == 0) out[0] = sw[0] + sw[1] + sw[2] + sw[3];
}

extern "C" void kernel_launch(void* const* d_in, const int* in_sizes, int n_in,
                              void* d_out, int out_size, void* d_ws, size_t ws_size,
                              hipStream_t stream) {
    const float* trans = (const float*)d_in[0];
    const float* feats = (const float*)d_in[1];
    const int*   mask  = (const int*)d_in[2];
    const int*   tags  = (const int*)d_in[3];
    float*       out   = (float*)d_out;
    float*       ws    = (float*)d_ws;

    hipLaunchKernelGGL(forward_kernel, dim3(2 * CRF_B), dim3(256), 0, stream,
                       trans, feats, mask, tags, ws);
    hipLaunchKernelGGL(combine_kernel, dim3(1), dim3(256), 0, stream, ws, out);
}